// Round 4
// baseline (44.580 us; speedup 1.0000x reference)
//
#include <hip/hip_runtime.h>
#include <math.h>

#define NGAUSS 2000
#define IMW 128
#define IMH 128
#define NPIX (IMW*IMH)
#define PSTRIDE 12
#define NSEG 32
#define PXT 2   // pixels per thread (same row)

// ---------------- preprocess: per-gaussian params ----------------
__global__ __launch_bounds__(256) void prep_kernel(
    const float* __restrict__ means3D, const float* __restrict__ covs3d,
    const float* __restrict__ colors, const float* __restrict__ opac,
    const float* __restrict__ Km, const float* __restrict__ Rm,
    const float* __restrict__ tv,
    float* __restrict__ params, float* __restrict__ depths)
{
    int i = blockIdx.x * 256 + threadIdx.x;
    if (i >= NGAUSS) return;

    float R0 = Rm[0], R1 = Rm[1], R2 = Rm[2];
    float R3 = Rm[3], R4 = Rm[4], R5 = Rm[5];
    float R6 = Rm[6], R7 = Rm[7], R8 = Rm[8];

    float mx = means3D[3*i+0], my = means3D[3*i+1], mz = means3D[3*i+2];
    float camx = R0*mx + R1*my + R2*mz + tv[0];
    float camy = R3*mx + R4*my + R5*mz + tv[1];
    float camz = R6*mx + R7*my + R8*mz + tv[2];

    float depth = fmaxf(camz, 1.0f);
    bool valid = (depth > 1.0f) && (depth < 50.0f);

    float fx = Km[0], cx = Km[2], fy = Km[4], cy = Km[5];
    float invz = 1.0f / camz;
    float m2x = (fx*camx + cx*camz) * invz;
    float m2y = (fy*camy + cy*camz) * invz;

    float J00 = fx*invz, J02 = -fx*camx*invz*invz;
    float J11 = fy*invz, J12 = -fy*camy*invz*invz;

    float S0 = covs3d[9*i+0], S1 = covs3d[9*i+1], S2 = covs3d[9*i+2];
    float S3 = covs3d[9*i+3], S4 = covs3d[9*i+4], S5 = covs3d[9*i+5];
    float S6 = covs3d[9*i+6], S7 = covs3d[9*i+7], S8 = covs3d[9*i+8];

    float RS0 = R0*S0 + R1*S3 + R2*S6;
    float RS1 = R0*S1 + R1*S4 + R2*S7;
    float RS2 = R0*S2 + R1*S5 + R2*S8;
    float RS3 = R3*S0 + R4*S3 + R5*S6;
    float RS4 = R3*S1 + R4*S4 + R5*S7;
    float RS5 = R3*S2 + R4*S5 + R5*S8;
    float RS6 = R6*S0 + R7*S3 + R8*S6;
    float RS7 = R6*S1 + R7*S4 + R8*S7;
    float RS8 = R6*S2 + R7*S5 + R8*S8;

    float Sc0 = RS0*R0 + RS1*R1 + RS2*R2;
    float Sc1 = RS0*R3 + RS1*R4 + RS2*R5;
    float Sc2 = RS0*R6 + RS1*R7 + RS2*R8;
    float Sc3 = RS3*R0 + RS4*R1 + RS5*R2;
    float Sc4 = RS3*R3 + RS4*R4 + RS5*R5;
    float Sc5 = RS3*R6 + RS4*R7 + RS5*R8;
    float Sc6 = RS6*R0 + RS7*R1 + RS8*R2;
    float Sc7 = RS6*R3 + RS7*R4 + RS8*R5;
    float Sc8 = RS6*R6 + RS7*R7 + RS8*R8;

    float A00 = J00*Sc0 + J02*Sc6;
    float A01 = J00*Sc1 + J02*Sc7;
    float A02 = J00*Sc2 + J02*Sc8;
    float A10 = J11*Sc3 + J12*Sc6;
    float A11 = J11*Sc4 + J12*Sc7;
    float A12 = J11*Sc5 + J12*Sc8;

    float a = A00*J00 + A02*J02 + 1e-4f;
    float b = A01*J11 + A02*J12;
    float c = A10*J00 + A12*J02;
    float d = A11*J11 + A12*J12 + 1e-4f;

    float det = a*d - b*c;
    float invdet = 1.0f / det;
    float q0 = d*invdet;
    float q1 = -(b + c)*invdet;
    float q2 = a*invdet;
    float c0 = opac[i] * 0.15915494309189535f / sqrtf(det);
    if (!valid) { m2x = 0.f; m2y = 0.f; q0 = 0.f; q1 = 0.f; q2 = 0.f; c0 = 0.f; }

    float cr = colors[3*i+0], cg = colors[3*i+1], cb = colors[3*i+2];
    float* P = params + i*PSTRIDE;
    P[0] = m2x;  P[1] = m2y;  P[2] = q0;   P[3] = q1;
    P[4] = q2;   P[5] = c0;   P[6] = cr;   P[7] = cg;
    P[8] = cb;   P[9] = depth; P[10] = 0.f; P[11] = 0.f;
    depths[i] = depth;
}

// ---------------- stable rank sort: one wave per gaussian ----------------
__global__ __launch_bounds__(64) void rank_kernel(
    const float* __restrict__ depths, const float* __restrict__ unsorted,
    float* __restrict__ sorted)
{
    int i = blockIdx.x;
    int lane = threadIdx.x;
    float di = depths[i];
    int rank = 0;
    for (int j = lane; j < NGAUSS; j += 64) {
        float dj = depths[j];
        rank += ((dj < di) || (dj == di && j < i)) ? 1 : 0;   // stable tie-break
    }
    #pragma unroll
    for (int o = 32; o > 0; o >>= 1) rank += __shfl_down(rank, o, 64);
    rank = __shfl(rank, 0, 64);
    if (lane < 3) {
        const float4* src = (const float4*)(unsorted + (size_t)i*PSTRIDE);
        float4* dst = (float4*)(sorted + (size_t)rank*PSTRIDE);
        dst[lane] = src[lane];
    }
}

// ---------------- render: per-pixel-pair, per-depth-segment compositing ----------------
// Params are wave-uniform -> read directly from global (scalar-load path), no LDS.
// Reference semantics: weight[0] = a_0;  weight[n>=1] = a_n * (1-a_n) * prod_{k<n}(1-a_k)
__global__ __launch_bounds__(256) void render_kernel(
    const float* __restrict__ sorted, float4* __restrict__ segOut, int perSeg)
{
    int tid = threadIdx.x;
    int seg = blockIdx.y;
    int p0 = (blockIdx.x*256 + tid) * PXT;       // two adjacent pixels, same row
    float px0 = (float)(p0 & (IMW-1));
    float px1 = px0 + 1.0f;
    float py  = (float)(p0 >> 7);

    float Cr0 = 0.f, Cg0 = 0.f, Cb0 = 0.f, T0 = 1.f;
    float Cr1 = 0.f, Cg1 = 0.f, Cb1 = 0.f, T1 = 1.f;

    int base = seg * perSeg;
    int cnt = min(perSeg, NGAUSS - base);
    const float* Pbase = sorted + (size_t)base*PSTRIDE;

    int n0 = 0;
    if (seg == 0) {
        // globally-first sorted gaussian: weight = alpha (no self (1-alpha) factor)
        const float* P = Pbase;
        float mX = P[0], mY = P[1], q0 = P[2], q1 = P[3], q2 = P[4];
        float c0 = P[5], cr = P[6], cg = P[7], cb = P[8];
        float dy = py - mY;
        float t1 = q1*dy, t2 = q2*dy*dy;
        float dx0 = px0 - mX, dx1 = px1 - mX;
        float e0 = fmaf(fmaf(q0,dx0,t1), dx0, t2);
        float e1 = fmaf(fmaf(q0,dx1,t1), dx1, t2);
        float a0 = c0 * __expf(-e0);
        float a1 = c0 * __expf(-e1);
        Cr0 = fmaf(a0, cr, Cr0); Cg0 = fmaf(a0, cg, Cg0); Cb0 = fmaf(a0, cb, Cb0); T0 -= a0;
        Cr1 = fmaf(a1, cr, Cr1); Cg1 = fmaf(a1, cg, Cg1); Cb1 = fmaf(a1, cb, Cb1); T1 -= a1;
        n0 = 1;
    }
    #pragma unroll 2
    for (int n = n0; n < cnt; ++n) {
        const float* P = Pbase + n*PSTRIDE;      // uniform address -> s_load
        float mX = P[0], mY = P[1], q0 = P[2], q1 = P[3], q2 = P[4];
        float c0 = P[5], cr = P[6], cg = P[7], cb = P[8];
        float dy = py - mY;
        float t1 = q1*dy, t2 = q2*dy*dy;

        float dx0 = px0 - mX;
        float e0 = fmaf(fmaf(q0,dx0,t1), dx0, t2);
        float g0 = __expf(-e0);
        float a0 = c0 * g0;
        float w0 = T0 * a0;
        float f0 = fmaf(-a0, w0, w0);            // T*alpha*(1-alpha)
        Cr0 = fmaf(f0, cr, Cr0); Cg0 = fmaf(f0, cg, Cg0); Cb0 = fmaf(f0, cb, Cb0);
        T0 -= w0;

        float dx1 = px1 - mX;
        float e1 = fmaf(fmaf(q0,dx1,t1), dx1, t2);
        float g1 = __expf(-e1);
        float a1 = c0 * g1;
        float w1 = T1 * a1;
        float f1 = fmaf(-a1, w1, w1);
        Cr1 = fmaf(f1, cr, Cr1); Cg1 = fmaf(f1, cg, Cg1); Cb1 = fmaf(f1, cb, Cb1);
        T1 -= w1;
    }
    segOut[(size_t)seg*NPIX + p0]     = make_float4(Cr0, Cg0, Cb0, T0);
    segOut[(size_t)seg*NPIX + p0 + 1] = make_float4(Cr1, Cg1, Cb1, T1);
}

// ---------------- combine segments in depth order ----------------
__global__ __launch_bounds__(256) void combine_kernel(
    const float4* __restrict__ segOut, float* __restrict__ out, int nSeg)
{
    int p = blockIdx.x*256 + threadIdx.x;
    float Cr = 0.f, Cg = 0.f, Cb = 0.f, T = 1.f;
    for (int s = 0; s < nSeg; ++s) {
        float4 v = segOut[(size_t)s*NPIX + p];
        Cr = fmaf(T, v.x, Cr);
        Cg = fmaf(T, v.y, Cg);
        Cb = fmaf(T, v.z, Cb);
        T *= v.w;
    }
    out[3*p+0] = Cr; out[3*p+1] = Cg; out[3*p+2] = Cb;
}

extern "C" void kernel_launch(void* const* d_in, const int* in_sizes, int n_in,
                              void* d_out, int out_size, void* d_ws, size_t ws_size,
                              hipStream_t stream)
{
    const float* means3D = (const float*)d_in[0];
    const float* covs3d  = (const float*)d_in[1];
    const float* colors  = (const float*)d_in[2];
    const float* opac    = (const float*)d_in[3];
    const float* Km      = (const float*)d_in[4];
    const float* Rm      = (const float*)d_in[5];
    const float* tv      = (const float*)d_in[6];

    float* ws       = (float*)d_ws;
    float* unsorted = ws;              // NGAUSS*12 = 24000 floats
    float* depths   = ws + 24000;      // 2000 floats
    float* sorted   = ws + 26000;      // 24000 floats
    float* segOut   = ws + 50000;      // nSeg*NPIX*4 floats

    int nSeg = NSEG;
    while (nSeg > 1 &&
           ws_size < ((size_t)50000 + (size_t)nSeg*NPIX*4) * sizeof(float))
        nSeg >>= 1;
    int perSeg = (NGAUSS + nSeg - 1) / nSeg;

    prep_kernel<<<(NGAUSS+255)/256, 256, 0, stream>>>(
        means3D, covs3d, colors, opac, Km, Rm, tv, unsorted, depths);
    rank_kernel<<<NGAUSS, 64, 0, stream>>>(depths, unsorted, sorted);
    dim3 rg(NPIX/(256*PXT), nSeg);
    render_kernel<<<rg, 256, 0, stream>>>(sorted, (float4*)segOut, perSeg);
    combine_kernel<<<NPIX/256, 256, 0, stream>>>((float4*)segOut, (float*)d_out, nSeg);
}

// Round 5
// 44.507 us; speedup vs baseline: 1.0016x; 1.0016x over previous
//
#include <hip/hip_runtime.h>
#include <math.h>

#define NGAUSS 2000
#define IMW 128
#define IMH 128
#define NPIX (IMW*IMH)
#define PSTRIDE 12
#define NSEG 64
#define PERSEG ((NGAUSS + NSEG - 1) / NSEG)   // 32
#define PXT 4   // pixels per thread (same row)

// ---------------- preprocess: per-gaussian params ----------------
// q0,q1,q2 are pre-scaled by -log2(e) so render uses exp2f directly.
__global__ __launch_bounds__(256) void prep_kernel(
    const float* __restrict__ means3D, const float* __restrict__ covs3d,
    const float* __restrict__ colors, const float* __restrict__ opac,
    const float* __restrict__ Km, const float* __restrict__ Rm,
    const float* __restrict__ tv,
    float* __restrict__ params, float* __restrict__ depths)
{
    int i = blockIdx.x * 256 + threadIdx.x;
    if (i >= NGAUSS) return;

    float R0 = Rm[0], R1 = Rm[1], R2 = Rm[2];
    float R3 = Rm[3], R4 = Rm[4], R5 = Rm[5];
    float R6 = Rm[6], R7 = Rm[7], R8 = Rm[8];

    float mx = means3D[3*i+0], my = means3D[3*i+1], mz = means3D[3*i+2];
    float camx = R0*mx + R1*my + R2*mz + tv[0];
    float camy = R3*mx + R4*my + R5*mz + tv[1];
    float camz = R6*mx + R7*my + R8*mz + tv[2];

    float depth = fmaxf(camz, 1.0f);
    bool valid = (depth > 1.0f) && (depth < 50.0f);

    float fx = Km[0], cx = Km[2], fy = Km[4], cy = Km[5];
    float invz = 1.0f / camz;
    float m2x = (fx*camx + cx*camz) * invz;
    float m2y = (fy*camy + cy*camz) * invz;

    float J00 = fx*invz, J02 = -fx*camx*invz*invz;
    float J11 = fy*invz, J12 = -fy*camy*invz*invz;

    float S0 = covs3d[9*i+0], S1 = covs3d[9*i+1], S2 = covs3d[9*i+2];
    float S3 = covs3d[9*i+3], S4 = covs3d[9*i+4], S5 = covs3d[9*i+5];
    float S6 = covs3d[9*i+6], S7 = covs3d[9*i+7], S8 = covs3d[9*i+8];

    float RS0 = R0*S0 + R1*S3 + R2*S6;
    float RS1 = R0*S1 + R1*S4 + R2*S7;
    float RS2 = R0*S2 + R1*S5 + R2*S8;
    float RS3 = R3*S0 + R4*S3 + R5*S6;
    float RS4 = R3*S1 + R4*S4 + R5*S7;
    float RS5 = R3*S2 + R4*S5 + R5*S8;
    float RS6 = R6*S0 + R7*S3 + R8*S6;
    float RS7 = R6*S1 + R7*S4 + R8*S7;
    float RS8 = R6*S2 + R7*S5 + R8*S8;

    float Sc0 = RS0*R0 + RS1*R1 + RS2*R2;
    float Sc1 = RS0*R3 + RS1*R4 + RS2*R5;
    float Sc2 = RS0*R6 + RS1*R7 + RS2*R8;
    float Sc3 = RS3*R0 + RS4*R1 + RS5*R2;
    float Sc4 = RS3*R3 + RS4*R4 + RS5*R5;
    float Sc5 = RS3*R6 + RS4*R7 + RS5*R8;
    float Sc6 = RS6*R0 + RS7*R1 + RS8*R2;
    float Sc7 = RS6*R3 + RS7*R4 + RS8*R5;
    float Sc8 = RS6*R6 + RS7*R7 + RS8*R8;

    float A00 = J00*Sc0 + J02*Sc6;
    float A01 = J00*Sc1 + J02*Sc7;
    float A02 = J00*Sc2 + J02*Sc8;
    float A10 = J11*Sc3 + J12*Sc6;
    float A11 = J11*Sc4 + J12*Sc7;
    float A12 = J11*Sc5 + J12*Sc8;

    float a = A00*J00 + A02*J02 + 1e-4f;
    float b = A01*J11 + A02*J12;
    float c = A10*J00 + A12*J02;
    float d = A11*J11 + A12*J12 + 1e-4f;

    float det = a*d - b*c;
    float invdet = 1.0f / det;
    const float NL2E = -1.4426950408889634f;   // -log2(e)
    float q0 = d*invdet * NL2E;
    float q1 = -(b + c)*invdet * NL2E;
    float q2 = a*invdet * NL2E;
    float c0 = opac[i] * 0.15915494309189535f / sqrtf(det);
    if (!valid) { m2x = 0.f; m2y = 0.f; q0 = 0.f; q1 = 0.f; q2 = 0.f; c0 = 0.f; }

    float cr = colors[3*i+0], cg = colors[3*i+1], cb = colors[3*i+2];
    float* P = params + i*PSTRIDE;
    P[0] = m2x;  P[1] = m2y;  P[2] = q0;   P[3] = q1;
    P[4] = q2;   P[5] = c0;   P[6] = cr;   P[7] = cg;
    P[8] = cb;   P[9] = depth; P[10] = 0.f; P[11] = 0.f;
    depths[i] = depth;
}

// ---------------- stable rank sort: one wave per gaussian ----------------
__global__ __launch_bounds__(64) void rank_kernel(
    const float* __restrict__ depths, const float* __restrict__ unsorted,
    float* __restrict__ sorted)
{
    int i = blockIdx.x;
    int lane = threadIdx.x;
    float di = depths[i];
    int rank = 0;
    for (int j = lane; j < NGAUSS; j += 64) {
        float dj = depths[j];
        rank += ((dj < di) || (dj == di && j < i)) ? 1 : 0;   // stable tie-break
    }
    #pragma unroll
    for (int o = 32; o > 0; o >>= 1) rank += __shfl_down(rank, o, 64);
    rank = __shfl(rank, 0, 64);
    if (lane < 3) {
        const float4* src = (const float4*)(unsorted + (size_t)i*PSTRIDE);
        float4* dst = (float4*)(sorted + (size_t)rank*PSTRIDE);
        dst[lane] = src[lane];
    }
}

// ---------------- render: 4 px/thread, whole segment in LDS, reg prefetch ----
// Reference semantics: weight[0] = a_0;  weight[n>=1] = a_n*(1-a_n)*prod_{k<n}(1-a_k)
__global__ __launch_bounds__(256) void render_kernel(
    const float* __restrict__ sorted, float4* __restrict__ segOut)
{
    __shared__ float4 sp[(PERSEG + 1) * 3];
    int tid = threadIdx.x;
    int seg = blockIdx.y;
    int base = seg * PERSEG;
    int cnt = NGAUSS - base; if (cnt > PERSEG) cnt = PERSEG; if (cnt < 0) cnt = 0;

    const float4* src = (const float4*)(sorted + (size_t)base*PSTRIDE);
    if (tid < cnt*3) sp[tid] = src[tid];
    if (tid < 3) sp[cnt*3 + tid] = make_float4(0.f, 0.f, 0.f, 0.f);
    __syncthreads();

    int p0 = (blockIdx.x*256 + tid) * PXT;
    float py = (float)(p0 >> 7);
    float pxj[PXT];
    #pragma unroll
    for (int j = 0; j < PXT; ++j) pxj[j] = (float)((p0 & (IMW-1)) + j);

    float Cr[PXT], Cg[PXT], Cb[PXT], T[PXT];
    #pragma unroll
    for (int j = 0; j < PXT; ++j) { Cr[j]=0.f; Cg[j]=0.f; Cb[j]=0.f; T[j]=1.f; }

    float4 a0, a1, a2;
    a0 = sp[0]; a1 = sp[1]; a2 = sp[2];
    int n0 = 0;
    if (seg == 0) {
        // globally-first sorted gaussian: weight = alpha (no self (1-alpha) factor)
        float dy = py - a0.y;
        float t1 = a0.w * dy;            // q1*dy
        float t2 = (a1.x * dy) * dy;     // q2*dy^2
        #pragma unroll
        for (int j = 0; j < PXT; ++j) {
            float dx = pxj[j] - a0.x;
            float e = fmaf(fmaf(a0.z, dx, t1), dx, t2);   // already -log2e scaled
            float al = a1.y * exp2f(e);
            Cr[j] = fmaf(al, a1.z, Cr[j]);
            Cg[j] = fmaf(al, a1.w, Cg[j]);
            Cb[j] = fmaf(al, a2.x, Cb[j]);
            T[j] -= al;
        }
        a0 = sp[3]; a1 = sp[4]; a2 = sp[5];
        n0 = 1;
    }
    for (int n = n0; n < cnt; ++n) {
        float4 b0 = sp[(n+1)*3+0];   // prefetch next gaussian (pad slot at end)
        float4 b1 = sp[(n+1)*3+1];
        float4 b2 = sp[(n+1)*3+2];
        float dy = py - a0.y;
        float t1 = a0.w * dy;
        float t2 = (a1.x * dy) * dy;
        #pragma unroll
        for (int j = 0; j < PXT; ++j) {
            float dx = pxj[j] - a0.x;
            float e = fmaf(fmaf(a0.z, dx, t1), dx, t2);
            float g = exp2f(e);
            float al = a1.y * g;          // alpha
            float w = T[j] * al;          // T*alpha
            float f = fmaf(-al, w, w);    // T*alpha*(1-alpha)
            Cr[j] = fmaf(f, a1.z, Cr[j]);
            Cg[j] = fmaf(f, a1.w, Cg[j]);
            Cb[j] = fmaf(f, a2.x, Cb[j]);
            T[j] -= w;                    // T *= (1-alpha)
        }
        a0 = b0; a1 = b1; a2 = b2;
    }
    size_t ob = (size_t)seg*NPIX + p0;
    #pragma unroll
    for (int j = 0; j < PXT; ++j)
        segOut[ob + j] = make_float4(Cr[j], Cg[j], Cb[j], T[j]);
}

// ---------------- combine segments in depth order ----------------
__global__ __launch_bounds__(256) void combine_kernel(
    const float4* __restrict__ segOut, float* __restrict__ out)
{
    int p = blockIdx.x*256 + threadIdx.x;
    float Cr = 0.f, Cg = 0.f, Cb = 0.f, T = 1.f;
    #pragma unroll 8
    for (int s = 0; s < NSEG; ++s) {
        float4 v = segOut[(size_t)s*NPIX + p];
        Cr = fmaf(T, v.x, Cr);
        Cg = fmaf(T, v.y, Cg);
        Cb = fmaf(T, v.z, Cb);
        T *= v.w;
    }
    out[3*p+0] = Cr; out[3*p+1] = Cg; out[3*p+2] = Cb;
}

extern "C" void kernel_launch(void* const* d_in, const int* in_sizes, int n_in,
                              void* d_out, int out_size, void* d_ws, size_t ws_size,
                              hipStream_t stream)
{
    const float* means3D = (const float*)d_in[0];
    const float* covs3d  = (const float*)d_in[1];
    const float* colors  = (const float*)d_in[2];
    const float* opac    = (const float*)d_in[3];
    const float* Km      = (const float*)d_in[4];
    const float* Rm      = (const float*)d_in[5];
    const float* tv      = (const float*)d_in[6];

    float* ws       = (float*)d_ws;
    float* unsorted = ws;              // NGAUSS*12 = 24000 floats
    float* depths   = ws + 24000;      // 2000 floats
    float* sorted   = ws + 26000;      // 24000 floats
    float* segOut   = ws + 50000;      // NSEG*NPIX*4 floats = 16.8 MB

    prep_kernel<<<(NGAUSS+255)/256, 256, 0, stream>>>(
        means3D, covs3d, colors, opac, Km, Rm, tv, unsorted, depths);
    rank_kernel<<<NGAUSS, 64, 0, stream>>>(depths, unsorted, sorted);
    dim3 rg(NPIX/(256*PXT), NSEG);
    render_kernel<<<rg, 256, 0, stream>>>(sorted, (float4*)segOut);
    combine_kernel<<<NPIX/256, 256, 0, stream>>>((float4*)segOut, (float*)d_out);
}

// Round 6
// 31.543 us; speedup vs baseline: 1.4133x; 1.4110x over previous
//
#include <hip/hip_runtime.h>
#include <math.h>

#define NGAUSS 2000
#define IMW 128
#define IMH 128
#define NPIX (IMW*IMH)
#define PSTRIDE 12
#define NSEG 32
#define PERSEG ((NGAUSS + NSEG - 1) / NSEG)   // 63
#define PXT 4   // pixels per thread (same row)

// ---------------- fused prep + stable rank sort + scatter ----------------
// One wave per gaussian. All lanes redundantly compute the per-gaussian
// params (cheap, SIMD); lanes cooperatively count rank by recomputing
// depths of a stride-64 slice; lanes 0..2 scatter 3 float4s to sorted[rank].
// Param layout (per gaussian, 3 x float4):
//   [0] = { m2x, m2y, s_cull, q0s }   s_cull = lambda_min(Q) * log2(e)
//   [1] = { q1s, q2s, c0,    cr  }   qXs pre-scaled by -log2(e) for exp2
//   [2] = { cg,  cb,  depth, 0   }
__global__ __launch_bounds__(64) void preprank_kernel(
    const float* __restrict__ means3D, const float* __restrict__ covs3d,
    const float* __restrict__ colors, const float* __restrict__ opac,
    const float* __restrict__ Km, const float* __restrict__ Rm,
    const float* __restrict__ tv, float* __restrict__ sorted)
{
    int i = blockIdx.x;
    int lane = threadIdx.x;

    float R0 = Rm[0], R1 = Rm[1], R2 = Rm[2];
    float R3 = Rm[3], R4 = Rm[4], R5 = Rm[5];
    float R6 = Rm[6], R7 = Rm[7], R8 = Rm[8];
    float t0 = tv[0], t1v = tv[1], t2 = tv[2];

    // ---- rank: recompute depth_j inline (identical expression for i and j) ----
    float mx = means3D[3*i+0], my = means3D[3*i+1], mz = means3D[3*i+2];
    float di = fmaxf(R6*mx + R7*my + R8*mz + t2, 1.0f);
    int rank = 0;
    for (int j = lane; j < NGAUSS; j += 64) {
        float jx = means3D[3*j+0], jy = means3D[3*j+1], jz = means3D[3*j+2];
        float dj = fmaxf(R6*jx + R7*jy + R8*jz + t2, 1.0f);
        bool lt = (j != i) && ((dj < di) || (dj == di && j < i));  // stable, self-safe
        rank += lt ? 1 : 0;
    }
    #pragma unroll
    for (int o = 32; o > 0; o >>= 1) rank += __shfl_down(rank, o, 64);
    rank = __shfl(rank, 0, 64);

    // ---- prep (redundant on all lanes) ----
    float camx = R0*mx + R1*my + R2*mz + t0;
    float camy = R3*mx + R4*my + R5*mz + t1v;
    float camz = R6*mx + R7*my + R8*mz + t2;
    float depth = fmaxf(camz, 1.0f);
    bool valid = (depth > 1.0f) && (depth < 50.0f);

    float fx = Km[0], cx = Km[2], fy = Km[4], cy = Km[5];
    float invz = 1.0f / camz;
    float m2x = (fx*camx + cx*camz) * invz;
    float m2y = (fy*camy + cy*camz) * invz;
    float J00 = fx*invz, J02 = -fx*camx*invz*invz;
    float J11 = fy*invz, J12 = -fy*camy*invz*invz;

    float S0 = covs3d[9*i+0], S1 = covs3d[9*i+1], S2 = covs3d[9*i+2];
    float S3 = covs3d[9*i+3], S4 = covs3d[9*i+4], S5 = covs3d[9*i+5];
    float S6 = covs3d[9*i+6], S7 = covs3d[9*i+7], S8 = covs3d[9*i+8];

    float RS0 = R0*S0 + R1*S3 + R2*S6;
    float RS1 = R0*S1 + R1*S4 + R2*S7;
    float RS2 = R0*S2 + R1*S5 + R2*S8;
    float RS3 = R3*S0 + R4*S3 + R5*S6;
    float RS4 = R3*S1 + R4*S4 + R5*S7;
    float RS5 = R3*S2 + R4*S5 + R5*S8;
    float RS6 = R6*S0 + R7*S3 + R8*S6;
    float RS7 = R6*S1 + R7*S4 + R8*S7;
    float RS8 = R6*S2 + R7*S5 + R8*S8;

    float Sc0 = RS0*R0 + RS1*R1 + RS2*R2;
    float Sc1 = RS0*R3 + RS1*R4 + RS2*R5;
    float Sc2 = RS0*R6 + RS1*R7 + RS2*R8;
    float Sc3 = RS3*R0 + RS4*R1 + RS5*R2;
    float Sc4 = RS3*R3 + RS4*R4 + RS5*R5;
    float Sc5 = RS3*R6 + RS4*R7 + RS5*R8;
    float Sc6 = RS6*R0 + RS7*R1 + RS8*R2;
    float Sc7 = RS6*R3 + RS7*R4 + RS8*R5;
    float Sc8 = RS6*R6 + RS7*R7 + RS8*R8;

    float A00 = J00*Sc0 + J02*Sc6;
    float A01 = J00*Sc1 + J02*Sc7;
    float A02 = J00*Sc2 + J02*Sc8;
    float A10 = J11*Sc3 + J12*Sc6;
    float A11 = J11*Sc4 + J12*Sc7;
    float A12 = J11*Sc5 + J12*Sc8;

    float a = A00*J00 + A02*J02 + 1e-4f;
    float b = A01*J11 + A02*J12;
    float c = A10*J00 + A12*J02;
    float d = A11*J11 + A12*J12 + 1e-4f;

    float det = a*d - b*c;
    float invdet = 1.0f / det;
    float q0u = d*invdet;
    float q1u = -(b + c)*invdet;
    float q2u = a*invdet;
    // smallest eigenvalue of [[q0u, q1u/2],[q1u/2, q2u]] for conservative cull
    float mh = 0.5f*(q0u + q2u);
    float dh = 0.5f*(q0u - q2u);
    float oh = 0.5f*q1u;
    float lmin = mh - sqrtf(dh*dh + oh*oh);
    const float L2E = 1.4426950408889634f;
    float s_cull = lmin * L2E;
    float q0 = -q0u * L2E;
    float q1 = -q1u * L2E;
    float q2 = -q2u * L2E;
    float c0 = opac[i] * 0.15915494309189535f / sqrtf(det);
    if (!valid) { m2x = 0.f; m2y = 0.f; q0 = 0.f; q1 = 0.f; q2 = 0.f; c0 = 0.f; s_cull = 3.0e38f; }

    float cr = colors[3*i+0], cg = colors[3*i+1], cb = colors[3*i+2];
    if (lane < 3) {
        float4 v = (lane == 0) ? make_float4(m2x, m2y, s_cull, q0)
                 : (lane == 1) ? make_float4(q1, q2, c0, cr)
                               : make_float4(cg, cb, depth, 0.f);
        ((float4*)(sorted + (size_t)rank*PSTRIDE))[lane] = v;
    }
}

// ---------------- render: 4 px/thread, segment in LDS, wave-uniform cull ----
// Reference semantics: weight[0] = a_0;  weight[n>=1] = a_n*(1-a_n)*prod_{k<n}(1-a_k)
__global__ __launch_bounds__(256) void render_kernel(
    const float* __restrict__ sorted, float4* __restrict__ segOut)
{
    __shared__ float4 sp[PERSEG * 3];
    int tid = threadIdx.x;
    int seg = blockIdx.y;
    int base = seg * PERSEG;
    int cnt = NGAUSS - base; if (cnt > PERSEG) cnt = PERSEG; if (cnt < 0) cnt = 0;

    const float4* src = (const float4*)(sorted + (size_t)base*PSTRIDE);
    if (tid < cnt*3) sp[tid] = src[tid];
    __syncthreads();

    int p0 = (blockIdx.x*256 + tid) * PXT;
    float py = (float)(p0 >> 7);
    float px0 = (float)(p0 & (IMW-1));
    // wave-uniform 2-row span for culling
    int wavebase = (blockIdx.x*256 + (tid & ~63)) * PXT;
    float ry0 = (float)(wavebase >> 7);      // rows ry0, ry0+1; cols 0..127

    float Cr[PXT], Cg[PXT], Cb[PXT], T[PXT];
    #pragma unroll
    for (int j = 0; j < PXT; ++j) { Cr[j]=0.f; Cg[j]=0.f; Cb[j]=0.f; T[j]=1.f; }

    int n0 = 0;
    if (seg == 0) {
        // globally-first sorted gaussian: weight = alpha (no self (1-alpha) factor)
        float4 a0 = sp[0], a1 = sp[1], a2 = sp[2];
        float dy = py - a0.y;
        float u1 = a1.x * dy;
        float u2 = (a1.y * dy) * dy;
        #pragma unroll
        for (int j = 0; j < PXT; ++j) {
            float dx = px0 + (float)j - a0.x;
            float e = fmaf(fmaf(a0.w, dx, u1), dx, u2);
            float al = a1.z * exp2f(e);
            Cr[j] = fmaf(al, a1.w, Cr[j]);
            Cg[j] = fmaf(al, a2.x, Cg[j]);
            Cb[j] = fmaf(al, a2.y, Cb[j]);
            T[j] -= al;
        }
        n0 = 1;
    }
    for (int n = n0; n < cnt; ++n) {
        float4 a0 = sp[n*3+0];
        // conservative wave-uniform cull: min dist^2 from mean to the
        // wave's 2-row x 128-col rectangle, scaled by lambda_min*log2e
        float dxm = fmaxf(0.f, fmaxf(-a0.x, a0.x - 127.f));
        float dym = fmaxf(0.f, fmaxf(ry0 - a0.y, a0.y - (ry0 + 1.f)));
        if (a0.z * fmaf(dxm, dxm, dym*dym) > 24.f) continue;  // alpha < c0*2^-24

        float4 a1 = sp[n*3+1], a2 = sp[n*3+2];
        float dy = py - a0.y;
        float u1 = a1.x * dy;
        float u2 = (a1.y * dy) * dy;
        #pragma unroll
        for (int j = 0; j < PXT; ++j) {
            float dx = px0 + (float)j - a0.x;
            float e = fmaf(fmaf(a0.w, dx, u1), dx, u2);
            float g = exp2f(e);
            float al = a1.z * g;          // alpha
            float w = T[j] * al;          // T*alpha
            float f = fmaf(-al, w, w);    // T*alpha*(1-alpha)
            Cr[j] = fmaf(f, a1.w, Cr[j]);
            Cg[j] = fmaf(f, a2.x, Cg[j]);
            Cb[j] = fmaf(f, a2.y, Cb[j]);
            T[j] -= w;                    // T *= (1-alpha)
        }
    }
    size_t ob = (size_t)seg*NPIX + p0;
    #pragma unroll
    for (int j = 0; j < PXT; ++j)
        segOut[ob + j] = make_float4(Cr[j], Cg[j], Cb[j], T[j]);
}

// ---------------- combine segments in depth order ----------------
__global__ __launch_bounds__(64) void combine_kernel(
    const float4* __restrict__ segOut, float* __restrict__ out)
{
    int p = blockIdx.x*64 + threadIdx.x;
    float Cr = 0.f, Cg = 0.f, Cb = 0.f, T = 1.f;
    #pragma unroll 8
    for (int s = 0; s < NSEG; ++s) {
        float4 v = segOut[(size_t)s*NPIX + p];
        Cr = fmaf(T, v.x, Cr);
        Cg = fmaf(T, v.y, Cg);
        Cb = fmaf(T, v.z, Cb);
        T *= v.w;
    }
    out[3*p+0] = Cr; out[3*p+1] = Cg; out[3*p+2] = Cb;
}

extern "C" void kernel_launch(void* const* d_in, const int* in_sizes, int n_in,
                              void* d_out, int out_size, void* d_ws, size_t ws_size,
                              hipStream_t stream)
{
    const float* means3D = (const float*)d_in[0];
    const float* covs3d  = (const float*)d_in[1];
    const float* colors  = (const float*)d_in[2];
    const float* opac    = (const float*)d_in[3];
    const float* Km      = (const float*)d_in[4];
    const float* Rm      = (const float*)d_in[5];
    const float* tv      = (const float*)d_in[6];

    float* ws     = (float*)d_ws;
    float* sorted = ws;            // NGAUSS*12 floats = 96 KB (16B aligned)
    float* segOut = ws + 24000;    // NSEG*NPIX*4 floats = 8.4 MB

    preprank_kernel<<<NGAUSS, 64, 0, stream>>>(
        means3D, covs3d, colors, opac, Km, Rm, tv, sorted);
    dim3 rg(NPIX/(256*PXT), NSEG);
    render_kernel<<<rg, 256, 0, stream>>>(sorted, (float4*)segOut);
    combine_kernel<<<NPIX/64, 64, 0, stream>>>((float4*)segOut, (float*)d_out);
}